// Round 6
// baseline (1536.931 us; speedup 1.0000x reference)
//
#include <hip/hip_runtime.h>
#include <hip/hip_bf16.h>
#include <math.h>

#define N_NODES 100000
#define N_EDGES 1600000
#define N_GRAPHS 2048
#define NCLS 204
#define EPS_BN 1e-5f
#define NBUCK ((N_NODES + 255) / 256)   // 391
#define BIN_CHUNK 8192
#define N8 ((size_t)N_NODES * 8)        // uints per activation slice
#define N16 ((size_t)N_NODES * 16)      // ushorts per activation slice

typedef __attribute__((ext_vector_type(8))) short short8;
typedef __attribute__((ext_vector_type(4))) float f32x4;

__device__ __forceinline__ float bf_lo(uint v) { union { uint i; float f; } c; c.i = v << 16; return c.f; }
__device__ __forceinline__ float bf_hi(uint v) { union { uint i; float f; } c; c.i = v & 0xffff0000u; return c.f; }
__device__ __forceinline__ ushort f2bf(float v) {
  __hip_bfloat16 b = __float2bfloat16(v);
  return *reinterpret_cast<ushort*>(&b);
}
__device__ __forceinline__ uint pack2(float a, float b) {
  return (uint)f2bf(a) | ((uint)f2bf(b) << 16);
}

// ---------------- CSR build (no per-node atomics) ----------------
// phase 1: bucket counts via LDS histogram
__global__ __launch_bounds__(256) void k_bin_count(const int* __restrict__ dst,
                                                   int* __restrict__ bcnt, int E) {
  __shared__ int hist[NBUCK];
  int t = threadIdx.x;
  int e0 = blockIdx.x * BIN_CHUNK;
  for (int b = t; b < NBUCK; b += 256) hist[b] = 0;
  __syncthreads();
  for (int e = e0 + t; e < min(e0 + BIN_CHUNK, E); e += 256)
    atomicAdd(&hist[dst[e] >> 8], 1);
  __syncthreads();
  for (int b = t; b < NBUCK; b += 256)
    if (hist[b] > 0) atomicAdd(&bcnt[b], hist[b]);
}

// phase 2: single-block scan of bucket counts -> bbase[0..NBUCK], bcur
__global__ __launch_bounds__(512) void k_bucket_scan(const int* __restrict__ bcnt,
                                                     int* __restrict__ bbase,
                                                     int* __restrict__ bcur) {
  __shared__ int sh[512];
  int t = threadIdx.x;
  int v = (t < NBUCK) ? bcnt[t] : 0;
  sh[t] = v;
  __syncthreads();
  for (int d = 1; d < 512; d <<= 1) {
    int x = (t >= d) ? sh[t - d] : 0;
    __syncthreads();
    sh[t] += x;
    __syncthreads();
  }
  if (t < NBUCK) {
    bbase[t + 1] = sh[t];
    int excl = sh[t] - v;
    bcur[t] = excl;
    if (t == 0) bbase[0] = 0;
  }
}

// phase 3: scatter (src,dst) into bucket-contiguous staging
__global__ __launch_bounds__(256) void k_bin(const int* __restrict__ src,
                                             const int* __restrict__ dst,
                                             int* __restrict__ cursor,
                                             uint2* __restrict__ staging, int E) {
  __shared__ int hist[NBUCK];
  __shared__ int base_s[NBUCK];
  int t = threadIdx.x;
  int e0 = blockIdx.x * BIN_CHUNK;
  for (int b = t; b < NBUCK; b += 256) hist[b] = 0;
  __syncthreads();
  for (int e = e0 + t; e < min(e0 + BIN_CHUNK, E); e += 256)
    atomicAdd(&hist[dst[e] >> 8], 1);
  __syncthreads();
  for (int b = t; b < NBUCK; b += 256) {
    int hh = hist[b];
    if (hh > 0) base_s[b] = atomicAdd(&cursor[b], hh);
    hist[b] = 0;
  }
  __syncthreads();
  for (int e = e0 + t; e < min(e0 + BIN_CHUNK, E); e += 256) {
    int d = dst[e];
    int b = d >> 8;
    int r = atomicAdd(&hist[b], 1);
    staging[base_s[b] + r] = make_uint2((uint)src[e], (uint)d);
  }
}

// phase 4: per bucket — degrees + row_ptr + place, all in LDS
__global__ __launch_bounds__(256) void k_place2(const uint2* __restrict__ staging,
                                                const int* __restrict__ bbase,
                                                int* __restrict__ row_ptr,
                                                int* __restrict__ csr, int nNodes, int E) {
  __shared__ int cnt[256];
  __shared__ int scn[256];
  __shared__ int cur[256];
  int t = threadIdx.x;
  int b = blockIdx.x;
  int n0 = b * 256;
  cnt[t] = 0;
  __syncthreads();
  int s = bbase[b], e = bbase[b + 1];
  for (int i = s + t; i < e; i += 256) atomicAdd(&cnt[staging[i].y - n0], 1);
  __syncthreads();
  int v = cnt[t];
  scn[t] = v;
  __syncthreads();
  for (int d = 1; d < 256; d <<= 1) {
    int x = (t >= d) ? scn[t - d] : 0;
    __syncthreads();
    scn[t] += x;
    __syncthreads();
  }
  int excl = scn[t] - v;
  if (n0 + t < nNodes) row_ptr[n0 + t] = s + excl;
  cur[t] = s + excl;
  __syncthreads();
  for (int i = s + t; i < e; i += 256) {
    uint2 ed = staging[i];
    int pos = atomicAdd(&cur[ed.y - n0], 1);
    csr[pos] = (int)ed.x;
  }
  if (b == 0 && t == 0) row_ptr[nNodes] = E;
}

// ---------------- conversions / weight prep ----------------
// h [N x 78] fp32 -> hb slice-major bf16: hb[slice][n][8 uints]
__global__ void k_conv_h(const float* __restrict__ h, uint* __restrict__ hb, int nNodes) {
  int j = blockIdx.x * blockDim.x + threadIdx.x;
  int slice = blockIdx.y;
  if (j < nNodes * 8) {
    int n = j >> 3, w = j & 7;
    int c = slice * 16 + 2 * w;
    float a = (c < 78) ? h[(size_t)n * 78 + c] : 0.0f;
    float b = (c + 1 < 78) ? h[(size_t)n * 78 + c + 1] : 0.0f;
    hb[(size_t)slice * N8 + j] = pack2(a, b);
  }
}

__global__ void k_prep_wt(const float* __restrict__ W, ushort* __restrict__ Wt, int K) {
  int i = blockIdx.x * blockDim.x + threadIdx.x;
  if (i < 128 * 128) {
    int n = i >> 7, k = i & 127;
    float v = (k < K) ? W[(size_t)k * 128 + n] : 0.0f;
    Wt[i] = f2bf(v);
  }
}

__global__ void k_prep_wt_gen(const float* __restrict__ W, int wld, int col_off, int nkeep,
                              int K, ushort* __restrict__ Wt, int total) {
  int i = blockIdx.x * blockDim.x + threadIdx.x;
  if (i < total) {
    int n = i / K, k = i - n * K;
    float v = (n < nkeep) ? W[(size_t)k * wld + col_off + n] : 0.0f;
    Wt[i] = f2bf(v);
  }
}

// ---------------- sliced GIN aggregation (XCD-resident), fused prev BN+ReLU ----------------
// slice = blockIdx.x & 7 -> XCD-pinned 16-channel slice (3.2MB, L2-resident).
// One wave per node: lane = slot(3b) | chpair(3b). M_s[n] = 2*f(y_s[n]) + sum f(y_s[src])
template <bool NRM>
__global__ __launch_bounds__(256) void k_agg_s(const uint* __restrict__ y,
                                               const int* __restrict__ row_ptr,
                                               const int* __restrict__ csr,
                                               const float* __restrict__ Ac,
                                               const float* __restrict__ Bc,
                                               uint* __restrict__ M, int nNodes) {
  int slice = blockIdx.x & 7;
  int nb = blockIdx.x >> 3;
  int wv = threadIdx.x >> 6;
  int l = threadIdx.x & 63;
  int n = nb * 4 + wv;
  if (n >= nNodes) return;
  int cp = l & 7;
  int slot = l >> 3;
  const uint* ys = y + (size_t)slice * N8;
  uint* Ms = M + (size_t)slice * N8;
  float A0 = 1.f, B0 = 0.f, A1 = 1.f, B1 = 0.f;
  if (NRM) {
    int c = slice * 16 + 2 * cp;
    A0 = Ac[c]; B0 = Bc[c]; A1 = Ac[c + 1]; B1 = Bc[c + 1];
  }
  auto flo = [&](uint v) { float x = bf_lo(v); return NRM ? fmaxf(x * A0 + B0, 0.f) : x; };
  auto fhi = [&](uint v) { float x = bf_hi(v); return NRM ? fmaxf(x * A1 + B1, 0.f) : x; };

  int s = row_ptr[n], e = row_ptr[n + 1];
  float a0 = 0.f, a1 = 0.f;
  if (slot == 0) {
    uint v = ys[(size_t)n * 8 + cp];
    a0 = 2.0f * flo(v);
    a1 = 2.0f * fhi(v);
  }
  for (int base = s; base < e; base += 8) {
    if (base + slot < e) {
      int idx = csr[base + slot];
      uint v = ys[(size_t)idx * 8 + cp];
      a0 += flo(v);
      a1 += fhi(v);
    }
  }
  a0 += __shfl_xor(a0, 8); a1 += __shfl_xor(a1, 8);
  a0 += __shfl_xor(a0, 16); a1 += __shfl_xor(a1, 16);
  a0 += __shfl_xor(a0, 32); a1 += __shfl_xor(a1, 32);
  if (slot == 0) Ms[(size_t)n * 8 + cp] = pack2(a0, a1);
}

// ---------------- node-layer MFMA GEMM + fused BN stats (slice-major A and Y) ----------------
#define SWZ(row, boff) ((boff) ^ (((row) & 7) << 4))
__global__ __launch_bounds__(256) void k_gemm_mfma(const uint* __restrict__ A,
                                                   const ushort* __restrict__ Wt,
                                                   const float* __restrict__ bias, float bscale,
                                                   ushort* __restrict__ Y, int Mrows,
                                                   float* __restrict__ gsum,
                                                   float* __restrict__ gsq) {
  __shared__ ushort As[128 * 128];
  __shared__ ushort Bs[128 * 128];
  __shared__ float sred[4][128], qred[4][128];
  int t = threadIdx.x;
  int r0 = blockIdx.x * 128;
  char* Ab = (char*)As;
  char* Bb = (char*)Bs;

  for (int it = 0; it < 8; it++) {
    int e = it * 256 + t;
    int row = e >> 4, seg = e & 15;
    uint4 va = make_uint4(0, 0, 0, 0);
    int gr = r0 + row;
    if (gr < Mrows)
      va = *reinterpret_cast<const uint4*>(A + (size_t)(seg >> 1) * N8 + (size_t)gr * 8 + (seg & 1) * 4);
    *reinterpret_cast<uint4*>(Ab + row * 256 + SWZ(row, seg * 16)) = va;
    uint4 vb = *reinterpret_cast<const uint4*>(Wt + (size_t)row * 128 + seg * 8);
    *reinterpret_cast<uint4*>(Bb + row * 256 + SWZ(row, seg * 16)) = vb;
  }
  __syncthreads();

  int wi = t >> 6;
  int l = t & 63;
  int lr = l & 15;
  int kp = l >> 4;

  f32x4 acc[2][8];
#pragma unroll
  for (int mi = 0; mi < 2; mi++)
#pragma unroll
    for (int ni = 0; ni < 8; ni++) acc[mi][ni] = (f32x4){0.f, 0.f, 0.f, 0.f};

#pragma unroll
  for (int ki = 0; ki < 4; ki++) {
    short8 a[2], b[8];
#pragma unroll
    for (int mi = 0; mi < 2; mi++) {
      int row = wi * 32 + mi * 16 + lr;
      a[mi] = *reinterpret_cast<const short8*>(Ab + row * 256 + SWZ(row, ki * 64 + kp * 16));
    }
#pragma unroll
    for (int ni = 0; ni < 8; ni++) {
      int row = ni * 16 + lr;
      b[ni] = *reinterpret_cast<const short8*>(Bb + row * 256 + SWZ(row, ki * 64 + kp * 16));
    }
#pragma unroll
    for (int mi = 0; mi < 2; mi++)
#pragma unroll
      for (int ni = 0; ni < 8; ni++)
        acc[mi][ni] = __builtin_amdgcn_mfma_f32_16x16x32_bf16(a[mi], b[ni], acc[mi][ni], 0, 0, 0);
  }

  float s_part[8], q_part[8];
#pragma unroll
  for (int ni = 0; ni < 8; ni++) { s_part[ni] = 0.f; q_part[ni] = 0.f; }

#pragma unroll
  for (int mi = 0; mi < 2; mi++) {
    int rbase = r0 + wi * 32 + mi * 16 + kp * 4;
#pragma unroll
    for (int ni = 0; ni < 8; ni++) {
      int col = ni * 16 + lr;
      float bb = bscale * bias[col];
      ushort* Ys = Y + (size_t)(col >> 4) * N16;
#pragma unroll
      for (int j = 0; j < 4; j++) {
        int r = rbase + j;
        if (r < Mrows) {
          float yv = acc[mi][ni][j] + bb;
          Ys[(size_t)r * 16 + (col & 15)] = f2bf(yv);
          s_part[ni] += yv;
          q_part[ni] += yv * yv;
        }
      }
    }
  }

#pragma unroll
  for (int ni = 0; ni < 8; ni++) {
    s_part[ni] += __shfl_xor(s_part[ni], 16, 64);
    s_part[ni] += __shfl_xor(s_part[ni], 32, 64);
    q_part[ni] += __shfl_xor(q_part[ni], 16, 64);
    q_part[ni] += __shfl_xor(q_part[ni], 32, 64);
  }
  if (kp == 0) {
#pragma unroll
    for (int ni = 0; ni < 8; ni++) {
      sred[wi][ni * 16 + lr] = s_part[ni];
      qred[wi][ni * 16 + lr] = q_part[ni];
    }
  }
  __syncthreads();
  if (t < 128) {
    float S = sred[0][t] + sred[1][t] + sred[2][t] + sred[3][t];
    float Q = qred[0][t] + qred[1][t] + qred[2][t] + qred[3][t];
    atomicAdd(&gsum[t], S);
    atomicAdd(&gsq[t], Q);
  }
}

// ---------------- head MFMA GEMM (dense layouts, generic M,K) ----------------
template <int AMODE, int OMODE>
__global__ __launch_bounds__(256) void k_head_mfma(const void* __restrict__ Aptr,
                                                   int Mrows, int K,
                                                   const ushort* __restrict__ Wt,
                                                   const float* __restrict__ bias,
                                                   int col_off, int ncols,
                                                   const float* __restrict__ nAc,
                                                   const float* __restrict__ nBc,
                                                   void* __restrict__ Yout, int Nld,
                                                   float* __restrict__ gsum,
                                                   float* __restrict__ gsq) {
  __shared__ ushort As[128 * 128];
  __shared__ ushort Bs[128 * 128];
  __shared__ float sred[4][128], qred[4][128];
  int t = threadIdx.x;
  int r0 = blockIdx.y * 128;
  int c0 = blockIdx.x * 128;
  char* Ab = (char*)As;
  char* Bb = (char*)Bs;

  int wi = t >> 6;
  int l = t & 63;
  int lr = l & 15;
  int kp = l >> 4;

  f32x4 acc[2][8];
#pragma unroll
  for (int mi = 0; mi < 2; mi++)
#pragma unroll
    for (int ni = 0; ni < 8; ni++) acc[mi][ni] = (f32x4){0.f, 0.f, 0.f, 0.f};

  for (int k0 = 0; k0 < K; k0 += 128) {
    if (k0) __syncthreads();
    for (int it = 0; it < 8; it++) {
      int e = it * 256 + t;
      int row = e >> 4, seg = e & 15;
      int gr = r0 + row;
      uint4 va;
      if (AMODE == 0) {
        const float* Af = (const float*)Aptr;
        float4 f0 = {0.f, 0.f, 0.f, 0.f}, f1 = {0.f, 0.f, 0.f, 0.f};
        if (gr < Mrows) {
          f0 = *reinterpret_cast<const float4*>(Af + (size_t)gr * K + k0 + seg * 8);
          f1 = *reinterpret_cast<const float4*>(Af + (size_t)gr * K + k0 + seg * 8 + 4);
        }
        va.x = pack2(f0.x, f0.y); va.y = pack2(f0.z, f0.w);
        va.z = pack2(f1.x, f1.y); va.w = pack2(f1.z, f1.w);
      } else {
        const uint* Au = (const uint*)Aptr;
        uint4 r4 = make_uint4(0, 0, 0, 0);
        if (gr < Mrows) r4 = *reinterpret_cast<const uint4*>(Au + (size_t)gr * (K >> 1) + ((k0 + seg * 8) >> 1));
        int c = k0 + seg * 8;
        uint uu[4] = {r4.x, r4.y, r4.z, r4.w};
#pragma unroll
        for (int q = 0; q < 4; q++) {
          float aa = fmaxf(bf_lo(uu[q]) * nAc[c + 2 * q] + nBc[c + 2 * q], 0.f);
          float bb = fmaxf(bf_hi(uu[q]) * nAc[c + 2 * q + 1] + nBc[c + 2 * q + 1], 0.f);
          uu[q] = pack2(aa, bb);
        }
        va = make_uint4(uu[0], uu[1], uu[2], uu[3]);
      }
      *reinterpret_cast<uint4*>(Ab + row * 256 + SWZ(row, seg * 16)) = va;
      uint4 vb = *reinterpret_cast<const uint4*>(Wt + (size_t)(c0 + row) * K + k0 + seg * 8);
      *reinterpret_cast<uint4*>(Bb + row * 256 + SWZ(row, seg * 16)) = vb;
    }
    __syncthreads();

#pragma unroll
    for (int ki = 0; ki < 4; ki++) {
      short8 a[2], b[8];
#pragma unroll
      for (int mi = 0; mi < 2; mi++) {
        int row = wi * 32 + mi * 16 + lr;
        a[mi] = *reinterpret_cast<const short8*>(Ab + row * 256 + SWZ(row, ki * 64 + kp * 16));
      }
#pragma unroll
      for (int ni = 0; ni < 8; ni++) {
        int row = ni * 16 + lr;
        b[ni] = *reinterpret_cast<const short8*>(Bb + row * 256 + SWZ(row, ki * 64 + kp * 16));
      }
#pragma unroll
      for (int mi = 0; mi < 2; mi++)
#pragma unroll
        for (int ni = 0; ni < 8; ni++)
          acc[mi][ni] = __builtin_amdgcn_mfma_f32_16x16x32_bf16(a[mi], b[ni], acc[mi][ni], 0, 0, 0);
    }
  }

  if (OMODE == 0) {
    float s_part[8], q_part[8];
#pragma unroll
    for (int ni = 0; ni < 8; ni++) { s_part[ni] = 0.f; q_part[ni] = 0.f; }
#pragma unroll
    for (int mi = 0; mi < 2; mi++) {
      int rbase = r0 + wi * 32 + mi * 16 + kp * 4;
#pragma unroll
      for (int ni = 0; ni < 8; ni++) {
        int gc = c0 + ni * 16 + lr;
        float bb = bias[col_off + gc];
#pragma unroll
        for (int j = 0; j < 4; j++) {
          int r = rbase + j;
          if (r < Mrows) {
            float yv = acc[mi][ni][j] + bb;
            ((ushort*)Yout)[(size_t)r * Nld + gc] = f2bf(yv);
            s_part[ni] += yv;
            q_part[ni] += yv * yv;
          }
        }
      }
    }
#pragma unroll
    for (int ni = 0; ni < 8; ni++) {
      s_part[ni] += __shfl_xor(s_part[ni], 16, 64);
      s_part[ni] += __shfl_xor(s_part[ni], 32, 64);
      q_part[ni] += __shfl_xor(q_part[ni], 16, 64);
      q_part[ni] += __shfl_xor(q_part[ni], 32, 64);
    }
    if (kp == 0) {
#pragma unroll
      for (int ni = 0; ni < 8; ni++) {
        sred[wi][ni * 16 + lr] = s_part[ni];
        qred[wi][ni * 16 + lr] = q_part[ni];
      }
    }
    __syncthreads();
    if (t < 128) {
      float S = sred[0][t] + sred[1][t] + sred[2][t] + sred[3][t];
      float Q = qred[0][t] + qred[1][t] + qred[2][t] + qred[3][t];
      atomicAdd(&gsum[c0 + t], S);
      atomicAdd(&gsq[c0 + t], Q);
    }
  } else {
#pragma unroll
    for (int mi = 0; mi < 2; mi++) {
      int rbase = r0 + wi * 32 + mi * 16 + kp * 4;
#pragma unroll
      for (int ni = 0; ni < 8; ni++) {
        int gc = c0 + ni * 16 + lr;
        if (gc < ncols) {
          float bb = bias[col_off + gc];
#pragma unroll
          for (int j = 0; j < 4; j++) {
            int r = rbase + j;
            if (r < Mrows) {
              float v = acc[mi][ni][j] + bb;
              ((float*)Yout)[(size_t)r * Nld + gc] = 1.0f / (1.0f + expf(-v));
            }
          }
        }
      }
    }
  }
}

__global__ void k_bnparams(const float* __restrict__ sum, const float* __restrict__ sumsq,
                           const float* __restrict__ gamma, const float* __restrict__ beta,
                           float* __restrict__ Ac, float* __restrict__ Bc,
                           int C, float invM) {
  int c = blockIdx.x * blockDim.x + threadIdx.x;
  if (c < C) {
    float mu = sum[c] * invM;
    float var = sumsq[c] * invM - mu * mu;
    float rs = rsqrtf(var + EPS_BN);
    float a = gamma[c] * rs;
    Ac[c] = a;
    Bc[c] = beta[c] - mu * a;
  }
}

// ---------------- graph readout (slice-major y): xg[g] = sum relu(y*A+B) ----------------
__global__ __launch_bounds__(64) void k_readout(const uint* __restrict__ y,
                                                const int* __restrict__ gid,
                                                const float* __restrict__ Ac,
                                                const float* __restrict__ Bc,
                                                float* __restrict__ xg, int nNodes) {
  int l = threadIdx.x;
  int n0 = blockIdx.x * 64;
  int n1 = min(n0 + 64, nNodes);
  if (n0 >= nNodes) return;
  const uint* ys = y + (size_t)(l >> 3) * N8;
  int w = l & 7;
  float A0 = Ac[2 * l], B0 = Bc[2 * l], A1 = Ac[2 * l + 1], B1 = Bc[2 * l + 1];
  float a0 = 0, a1 = 0;
  int cur = gid[n0];
  for (int n = n0; n < n1; n++) {
    int g = gid[n];
    if (g != cur) {
      atomicAdd(&xg[(size_t)cur * 128 + 2 * l], a0);
      atomicAdd(&xg[(size_t)cur * 128 + 2 * l + 1], a1);
      a0 = 0; a1 = 0; cur = g;
    }
    uint v = ys[(size_t)n * 8 + w];
    a0 += fmaxf(bf_lo(v) * A0 + B0, 0.f);
    a1 += fmaxf(bf_hi(v) * A1 + B1, 0.f);
  }
  atomicAdd(&xg[(size_t)cur * 128 + 2 * l], a0);
  atomicAdd(&xg[(size_t)cur * 128 + 2 * l + 1], a1);
}

extern "C" void kernel_launch(void* const* d_in, const int* in_sizes, int n_in,
                              void* d_out, int out_size, void* d_ws, size_t ws_size,
                              hipStream_t stream) {
  const float* h    = (const float*)d_in[0];
  const int*   esrc = (const int*)d_in[1];
  const int*   edst = (const int*)d_in[2];
  const int*   gid  = (const int*)d_in[3];
  const float* W1   = (const float*)d_in[4];
  const float* b1   = (const float*)d_in[5];
  const float* g1g  = (const float*)d_in[6];
  const float* g1b  = (const float*)d_in[7];
  const float* Wg   = (const float*)d_in[8];
  const float* bg   = (const float*)d_in[9];
  const float* gg   = (const float*)d_in[10];
  const float* gb   = (const float*)d_in[11];
  const float* fc1W = (const float*)d_in[12];
  const float* fc1b = (const float*)d_in[13];
  const float* bn1g = (const float*)d_in[14];
  const float* bn1b = (const float*)d_in[15];
  const float* linW = (const float*)d_in[16];
  const float* linb = (const float*)d_in[17];
  const float* lbng = (const float*)d_in[18];
  const float* lbnb = (const float*)d_in[19];
  const float* fc2W = (const float*)d_in[20];
  const float* fc2b = (const float*)d_in[21];
  float* out = (float*)d_out;

  char* p = (char*)d_ws;
  auto alloc = [&](size_t bytes) {
    char* q = p;
    p += (bytes + 255) & ~(size_t)255;
    return q;
  };
  int* row_ptr = (int*)alloc((N_NODES + 1) * sizeof(int));
  int* bcnt    = (int*)alloc(NBUCK * sizeof(int));
  int* bbase   = (int*)alloc((NBUCK + 1) * sizeof(int));
  int* bcur    = (int*)alloc(NBUCK * sizeof(int));
  int* csr     = (int*)alloc(N_EDGES * sizeof(int));
  uint* hb     = (uint*)alloc(8 * N8 * sizeof(uint));
  uint* Mb     = (uint*)alloc(8 * N8 * sizeof(uint));
  uint* yb     = (uint*)alloc(8 * N8 * sizeof(uint));
  ushort* Wt   = (ushort*)alloc(5 * 128 * 128 * sizeof(ushort));
  ushort* fc1Wt = (ushort*)alloc(512 * 128 * sizeof(ushort));
  ushort* linWt = (ushort*)alloc(256 * 512 * sizeof(ushort));
  ushort* fc2Wt = (ushort*)alloc(256 * 256 * sizeof(ushort));
  float* ssum  = (float*)alloc(512 * sizeof(float));
  float* ssq   = (float*)alloc(512 * sizeof(float));
  float* Ac    = (float*)alloc(512 * sizeof(float));
  float* Bc    = (float*)alloc(512 * sizeof(float));
  float* xg    = (float*)alloc((size_t)N_GRAPHS * 128 * sizeof(float));
  uint* y1b    = (uint*)alloc((size_t)N_GRAPHS * 256 * sizeof(uint));
  uint* y2b    = (uint*)alloc((size_t)N_GRAPHS * 128 * sizeof(uint));
  uint2* staging = (uint2*)Mb;  // aliases Mb (dead until the layer loop)

  // ---- prep: conversions + CSR build ----
  {
    dim3 g((N_NODES * 8 + 255) / 256, 8);
    k_conv_h<<<g, 256, 0, stream>>>(h, hb, N_NODES);
  }
  k_prep_wt<<<64, 256, 0, stream>>>(W1, Wt, 78);
  for (int l = 0; l < 4; l++)
    k_prep_wt<<<64, 256, 0, stream>>>(Wg + (size_t)l * 128 * 128, Wt + (size_t)(l + 1) * 128 * 128, 128);
  k_prep_wt_gen<<<(512 * 128 + 255) / 256, 256, 0, stream>>>(fc1W, 512, 0, 512, 128, fc1Wt, 512 * 128);
  k_prep_wt_gen<<<(256 * 512 + 255) / 256, 256, 0, stream>>>(linW, 256, 0, 256, 512, linWt, 256 * 512);
  k_prep_wt_gen<<<(256 * 256 + 255) / 256, 256, 0, stream>>>(fc2W, 408, 204, 204, 256, fc2Wt, 256 * 256);

  hipMemsetAsync(bcnt, 0, NBUCK * sizeof(int), stream);
  k_bin_count<<<(N_EDGES + BIN_CHUNK - 1) / BIN_CHUNK, 256, 0, stream>>>(edst, bcnt, N_EDGES);
  k_bucket_scan<<<1, 512, 0, stream>>>(bcnt, bbase, bcur);
  k_bin<<<(N_EDGES + BIN_CHUNK - 1) / BIN_CHUNK, 256, 0, stream>>>(esrc, edst, bcur,
                                                                   staging, N_EDGES);
  k_place2<<<NBUCK, 256, 0, stream>>>(staging, bbase, row_ptr, csr, N_NODES, N_EDGES);

  const float invN = 1.0f / (float)N_NODES;
  const float invG = 1.0f / (float)N_GRAPHS;

  // ---- 5 GIN layers ----
  const int aggGrid = ((N_NODES + 3) / 4) * 8;
  for (int layer = 0; layer < 5; layer++) {
    const ushort* Wl = Wt + (size_t)layer * 128 * 128;
    const float* bl  = (layer == 0) ? b1 : bg + (size_t)(layer - 1) * 128;
    const float* gl  = (layer == 0) ? g1g : gg + (size_t)(layer - 1) * 128;
    const float* bl2 = (layer == 0) ? g1b : gb + (size_t)(layer - 1) * 128;

    if (layer == 0)
      k_agg_s<false><<<aggGrid, 256, 0, stream>>>(hb, row_ptr, csr, nullptr, nullptr,
                                                  Mb, N_NODES);
    else
      k_agg_s<true><<<aggGrid, 256, 0, stream>>>(yb, row_ptr, csr, Ac, Bc, Mb, N_NODES);
    hipMemsetAsync(ssum, 0, 128 * sizeof(float), stream);
    hipMemsetAsync(ssq, 0, 128 * sizeof(float), stream);
    k_gemm_mfma<<<(N_NODES + 127) / 128, 256, 0, stream>>>(Mb, Wl, bl, 2.0f,
                                                           (ushort*)yb, N_NODES, ssum, ssq);
    k_bnparams<<<1, 128, 0, stream>>>(ssum, ssq, gl, bl2, Ac, Bc, 128, invN);
  }

  // ---- readout (applies layer-5 BN+ReLU inline) ----
  hipMemsetAsync(xg, 0, (size_t)N_GRAPHS * 128 * sizeof(float), stream);
  k_readout<<<(N_NODES + 63) / 64, 64, 0, stream>>>(yb, gid, Ac, Bc, xg, N_NODES);

  // ---- fc1 (128 -> 512): fp32 A, fused stats ----
  hipMemsetAsync(ssum, 0, 512 * sizeof(float), stream);
  hipMemsetAsync(ssq, 0, 512 * sizeof(float), stream);
  k_head_mfma<0, 0><<<dim3(4, 16), 256, 0, stream>>>(xg, N_GRAPHS, 128, fc1Wt, fc1b, 0, 512,
                                                     nullptr, nullptr, y1b, 512, ssum, ssq);
  k_bnparams<<<1, 512, 0, stream>>>(ssum, ssq, bn1g, bn1b, Ac, Bc, 512, invG);

  // ---- lin (512 -> 256): bf16 A + inline bn1/relu, fused stats ----
  hipMemsetAsync(ssum, 0, 256 * sizeof(float), stream);
  hipMemsetAsync(ssq, 0, 256 * sizeof(float), stream);
  k_head_mfma<1, 0><<<dim3(2, 16), 256, 0, stream>>>(y1b, N_GRAPHS, 512, linWt, linb, 0, 256,
                                                     Ac, Bc, y2b, 256, ssum, ssq);
  k_bnparams<<<1, 256, 0, stream>>>(ssum, ssq, lbng, lbnb, Ac, Bc, 256, invG);

  // ---- fc2 (256 -> 204): bf16 A + inline lbn/relu, sigmoid, write out ----
  k_head_mfma<1, 1><<<dim3(2, 16), 256, 0, stream>>>(y2b, N_GRAPHS, 256, fc2Wt, fc2b, 204, NCLS,
                                                     Ac, Bc, out, NCLS, nullptr, nullptr);
}

// Round 7
// 1201.534 us; speedup vs baseline: 1.2791x; 1.2791x over previous
//
#include <hip/hip_runtime.h>
#include <hip/hip_bf16.h>
#include <math.h>

#define N_NODES 100000
#define N_EDGES 1600000
#define N_GRAPHS 2048
#define NCLS 204
#define EPS_BN 1e-5f
#define NBUCK ((N_NODES + 255) / 256)   // 391
#define BIN_CHUNK 8192

typedef __attribute__((ext_vector_type(8))) short short8;
typedef __attribute__((ext_vector_type(4))) float f32x4;

__device__ __forceinline__ float bf_lo(uint v) { union { uint i; float f; } c; c.i = v << 16; return c.f; }
__device__ __forceinline__ float bf_hi(uint v) { union { uint i; float f; } c; c.i = v & 0xffff0000u; return c.f; }
__device__ __forceinline__ ushort f2bf(float v) {
  __hip_bfloat16 b = __float2bfloat16(v);
  return *reinterpret_cast<ushort*>(&b);
}
__device__ __forceinline__ uint pack2(float a, float b) {
  return (uint)f2bf(a) | ((uint)f2bf(b) << 16);
}

// ---------------- CSR build (round-6 version, no per-node atomics) ----------------
__global__ __launch_bounds__(256) void k_bin_count(const int* __restrict__ dst,
                                                   int* __restrict__ bcnt, int E) {
  __shared__ int hist[NBUCK];
  int t = threadIdx.x;
  int e0 = blockIdx.x * BIN_CHUNK;
  for (int b = t; b < NBUCK; b += 256) hist[b] = 0;
  __syncthreads();
  for (int e = e0 + t; e < min(e0 + BIN_CHUNK, E); e += 256)
    atomicAdd(&hist[dst[e] >> 8], 1);
  __syncthreads();
  for (int b = t; b < NBUCK; b += 256)
    if (hist[b] > 0) atomicAdd(&bcnt[b], hist[b]);
}

__global__ __launch_bounds__(512) void k_bucket_scan(const int* __restrict__ bcnt,
                                                     int* __restrict__ bbase,
                                                     int* __restrict__ bcur) {
  __shared__ int sh[512];
  int t = threadIdx.x;
  int v = (t < NBUCK) ? bcnt[t] : 0;
  sh[t] = v;
  __syncthreads();
  for (int d = 1; d < 512; d <<= 1) {
    int x = (t >= d) ? sh[t - d] : 0;
    __syncthreads();
    sh[t] += x;
    __syncthreads();
  }
  if (t < NBUCK) {
    bbase[t + 1] = sh[t];
    bcur[t] = sh[t] - v;
    if (t == 0) bbase[0] = 0;
  }
}

__global__ __launch_bounds__(256) void k_bin(const int* __restrict__ src,
                                             const int* __restrict__ dst,
                                             int* __restrict__ cursor,
                                             uint2* __restrict__ staging, int E) {
  __shared__ int hist[NBUCK];
  __shared__ int base_s[NBUCK];
  int t = threadIdx.x;
  int e0 = blockIdx.x * BIN_CHUNK;
  for (int b = t; b < NBUCK; b += 256) hist[b] = 0;
  __syncthreads();
  for (int e = e0 + t; e < min(e0 + BIN_CHUNK, E); e += 256)
    atomicAdd(&hist[dst[e] >> 8], 1);
  __syncthreads();
  for (int b = t; b < NBUCK; b += 256) {
    int hh = hist[b];
    if (hh > 0) base_s[b] = atomicAdd(&cursor[b], hh);
    hist[b] = 0;
  }
  __syncthreads();
  for (int e = e0 + t; e < min(e0 + BIN_CHUNK, E); e += 256) {
    int d = dst[e];
    int b = d >> 8;
    int r = atomicAdd(&hist[b], 1);
    staging[base_s[b] + r] = make_uint2((uint)src[e], (uint)d);
  }
}

__global__ __launch_bounds__(256) void k_place2(const uint2* __restrict__ staging,
                                                const int* __restrict__ bbase,
                                                int* __restrict__ row_ptr,
                                                int* __restrict__ csr, int nNodes, int E) {
  __shared__ int cnt[256];
  __shared__ int scn[256];
  __shared__ int cur[256];
  int t = threadIdx.x;
  int b = blockIdx.x;
  int n0 = b * 256;
  cnt[t] = 0;
  __syncthreads();
  int s = bbase[b], e = bbase[b + 1];
  for (int i = s + t; i < e; i += 256) atomicAdd(&cnt[staging[i].y - n0], 1);
  __syncthreads();
  int v = cnt[t];
  scn[t] = v;
  __syncthreads();
  for (int d = 1; d < 256; d <<= 1) {
    int x = (t >= d) ? scn[t - d] : 0;
    __syncthreads();
    scn[t] += x;
    __syncthreads();
  }
  int excl = scn[t] - v;
  if (n0 + t < nNodes) row_ptr[n0 + t] = s + excl;
  cur[t] = s + excl;
  __syncthreads();
  for (int i = s + t; i < e; i += 256) {
    uint2 ed = staging[i];
    int pos = atomicAdd(&cur[ed.y - n0], 1);
    csr[pos] = (int)ed.x;
  }
  if (b == 0 && t == 0) row_ptr[nNodes] = E;
}

// ---------------- conversions / weight prep (dense layouts) ----------------
__global__ void k_conv_h(const float* __restrict__ h, uint* __restrict__ hb, int nNodes) {
  int i = blockIdx.x * blockDim.x + threadIdx.x;
  if (i < nNodes * 64) {
    int n = i >> 6, cp = i & 63;
    int c = cp * 2;
    float a = (c < 78) ? h[(size_t)n * 78 + c] : 0.0f;
    float b = (c + 1 < 78) ? h[(size_t)n * 78 + c + 1] : 0.0f;
    hb[i] = pack2(a, b);
  }
}

__global__ void k_prep_wt(const float* __restrict__ W, ushort* __restrict__ Wt, int K) {
  int i = blockIdx.x * blockDim.x + threadIdx.x;
  if (i < 128 * 128) {
    int n = i >> 7, k = i & 127;
    float v = (k < K) ? W[(size_t)k * 128 + n] : 0.0f;
    Wt[i] = f2bf(v);
  }
}

__global__ void k_prep_wt_gen(const float* __restrict__ W, int wld, int col_off, int nkeep,
                              int K, ushort* __restrict__ Wt, int total) {
  int i = blockIdx.x * blockDim.x + threadIdx.x;
  if (i < total) {
    int n = i / K, k = i - n * K;
    float v = (n < nkeep) ? W[(size_t)k * wld + col_off + n] : 0.0f;
    Wt[i] = f2bf(v);
  }
}

// ---------------- fused GIN layer: agg (+prev BN/ReLU) -> LDS -> MFMA -> Y + stats ----------------
// X dense [n][64] uints (bf16x2, pre-norm). Y dense [n][128] ushorts (pre-norm out).
#define SWZ(row, boff) ((boff) ^ (((row) & 7) << 4))
template <bool NRM>
__global__ __launch_bounds__(256) void k_gin_fused(const uint* __restrict__ X,
                                                   const int* __restrict__ row_ptr,
                                                   const int* __restrict__ csr,
                                                   const ushort* __restrict__ Wt,
                                                   const float* __restrict__ bias, float bscale,
                                                   const float* __restrict__ Ac,
                                                   const float* __restrict__ Bc,
                                                   ushort* __restrict__ Y, int Mrows,
                                                   float* __restrict__ gsum,
                                                   float* __restrict__ gsq) {
  __shared__ ushort As[128 * 128];
  __shared__ ushort Bs[128 * 128];
  __shared__ float sred[4][128], qred[4][128];
  int t = threadIdx.x;
  int r0 = blockIdx.x * 128;
  char* Ab = (char*)As;
  char* Bb = (char*)Bs;
  int wv = t >> 6;
  int l = t & 63;

  // stage B (weights)
  for (int it = 0; it < 8; it++) {
    int e = it * 256 + t;
    int row = e >> 4, seg = e & 15;
    uint4 vb = *reinterpret_cast<const uint4*>(Wt + (size_t)row * 128 + seg * 8);
    *reinterpret_cast<uint4*>(Bb + row * 256 + SWZ(row, seg * 16)) = vb;
  }

  // stage A by aggregation: wave wv handles rows wv*32 .. wv*32+31
  float A0 = 1.f, B0 = 0.f, A1 = 1.f, B1 = 0.f;
  if (NRM) { A0 = Ac[2 * l]; B0 = Bc[2 * l]; A1 = Ac[2 * l + 1]; B1 = Bc[2 * l + 1]; }
  auto flo = [&](uint v) { float x = bf_lo(v); return NRM ? fmaxf(x * A0 + B0, 0.f) : x; };
  auto fhi = [&](uint v) { float x = bf_hi(v); return NRM ? fmaxf(x * A1 + B1, 0.f) : x; };

  for (int i = 0; i < 32; i++) {
    int row = wv * 32 + i;
    int n = r0 + row;
    float a0 = 0.f, a1 = 0.f;
    if (n < Mrows) {
      uint self = X[(size_t)n * 64 + l];
      a0 = 2.0f * flo(self);
      a1 = 2.0f * fhi(self);
      int s = row_ptr[n], e = row_ptr[n + 1];
      for (int base = s; base < e; base += 64) {
        int cnt = e - base;
        if (cnt > 64) cnt = 64;
        int myidx = (base + l < e) ? csr[base + l] : 0;
        int j = 0;
        for (; j + 4 <= cnt; j += 4) {
          int i0 = __shfl(myidx, j);
          int i1 = __shfl(myidx, j + 1);
          int i2 = __shfl(myidx, j + 2);
          int i3 = __shfl(myidx, j + 3);
          uint v0 = X[(size_t)i0 * 64 + l];
          uint v1 = X[(size_t)i1 * 64 + l];
          uint v2 = X[(size_t)i2 * 64 + l];
          uint v3 = X[(size_t)i3 * 64 + l];
          a0 += flo(v0) + flo(v1) + flo(v2) + flo(v3);
          a1 += fhi(v0) + fhi(v1) + fhi(v2) + fhi(v3);
        }
        for (; j < cnt; j++) {
          int ii = __shfl(myidx, j);
          uint v = X[(size_t)ii * 64 + l];
          a0 += flo(v);
          a1 += fhi(v);
        }
      }
    }
    // uint write lands inside the correct swizzled 16B chunk (XOR touches bits 4-6 only)
    *reinterpret_cast<uint*>(Ab + row * 256 + SWZ(row, l * 4)) = pack2(a0, a1);
  }
  __syncthreads();

  // MFMA (proven 4-wave body)
  int wi = wv;
  int lr = l & 15;
  int kp = l >> 4;

  f32x4 acc[2][8];
#pragma unroll
  for (int mi = 0; mi < 2; mi++)
#pragma unroll
    for (int ni = 0; ni < 8; ni++) acc[mi][ni] = (f32x4){0.f, 0.f, 0.f, 0.f};

#pragma unroll
  for (int ki = 0; ki < 4; ki++) {
    short8 a[2], b[8];
#pragma unroll
    for (int mi = 0; mi < 2; mi++) {
      int row = wi * 32 + mi * 16 + lr;
      a[mi] = *reinterpret_cast<const short8*>(Ab + row * 256 + SWZ(row, ki * 64 + kp * 16));
    }
#pragma unroll
    for (int ni = 0; ni < 8; ni++) {
      int row = ni * 16 + lr;
      b[ni] = *reinterpret_cast<const short8*>(Bb + row * 256 + SWZ(row, ki * 64 + kp * 16));
    }
#pragma unroll
    for (int mi = 0; mi < 2; mi++)
#pragma unroll
      for (int ni = 0; ni < 8; ni++)
        acc[mi][ni] = __builtin_amdgcn_mfma_f32_16x16x32_bf16(a[mi], b[ni], acc[mi][ni], 0, 0, 0);
  }

  float s_part[8], q_part[8];
#pragma unroll
  for (int ni = 0; ni < 8; ni++) { s_part[ni] = 0.f; q_part[ni] = 0.f; }

#pragma unroll
  for (int mi = 0; mi < 2; mi++) {
    int rbase = r0 + wi * 32 + mi * 16 + kp * 4;
#pragma unroll
    for (int ni = 0; ni < 8; ni++) {
      int col = ni * 16 + lr;
      float bb = bscale * bias[col];
#pragma unroll
      for (int j = 0; j < 4; j++) {
        int r = rbase + j;
        if (r < Mrows) {
          float yv = acc[mi][ni][j] + bb;
          Y[(size_t)r * 128 + col] = f2bf(yv);
          s_part[ni] += yv;
          q_part[ni] += yv * yv;
        }
      }
    }
  }

#pragma unroll
  for (int ni = 0; ni < 8; ni++) {
    s_part[ni] += __shfl_xor(s_part[ni], 16, 64);
    s_part[ni] += __shfl_xor(s_part[ni], 32, 64);
    q_part[ni] += __shfl_xor(q_part[ni], 16, 64);
    q_part[ni] += __shfl_xor(q_part[ni], 32, 64);
  }
  if (kp == 0) {
#pragma unroll
    for (int ni = 0; ni < 8; ni++) {
      sred[wi][ni * 16 + lr] = s_part[ni];
      qred[wi][ni * 16 + lr] = q_part[ni];
    }
  }
  __syncthreads();
  if (t < 128) {
    float S = sred[0][t] + sred[1][t] + sred[2][t] + sred[3][t];
    float Q = qred[0][t] + qred[1][t] + qred[2][t] + qred[3][t];
    atomicAdd(&gsum[t], S);
    atomicAdd(&gsq[t], Q);
  }
}

// ---------------- head MFMA GEMM (round-5 version, unchanged) ----------------
template <int AMODE, int OMODE>
__global__ __launch_bounds__(256) void k_head_mfma(const void* __restrict__ Aptr,
                                                   int Mrows, int K,
                                                   const ushort* __restrict__ Wt,
                                                   const float* __restrict__ bias,
                                                   int col_off, int ncols,
                                                   const float* __restrict__ nAc,
                                                   const float* __restrict__ nBc,
                                                   void* __restrict__ Yout, int Nld,
                                                   float* __restrict__ gsum,
                                                   float* __restrict__ gsq) {
  __shared__ ushort As[128 * 128];
  __shared__ ushort Bs[128 * 128];
  __shared__ float sred[4][128], qred[4][128];
  int t = threadIdx.x;
  int r0 = blockIdx.y * 128;
  int c0 = blockIdx.x * 128;
  char* Ab = (char*)As;
  char* Bb = (char*)Bs;

  int wi = t >> 6;
  int l = t & 63;
  int lr = l & 15;
  int kp = l >> 4;

  f32x4 acc[2][8];
#pragma unroll
  for (int mi = 0; mi < 2; mi++)
#pragma unroll
    for (int ni = 0; ni < 8; ni++) acc[mi][ni] = (f32x4){0.f, 0.f, 0.f, 0.f};

  for (int k0 = 0; k0 < K; k0 += 128) {
    if (k0) __syncthreads();
    for (int it = 0; it < 8; it++) {
      int e = it * 256 + t;
      int row = e >> 4, seg = e & 15;
      int gr = r0 + row;
      uint4 va;
      if (AMODE == 0) {
        const float* Af = (const float*)Aptr;
        float4 f0 = {0.f, 0.f, 0.f, 0.f}, f1 = {0.f, 0.f, 0.f, 0.f};
        if (gr < Mrows) {
          f0 = *reinterpret_cast<const float4*>(Af + (size_t)gr * K + k0 + seg * 8);
          f1 = *reinterpret_cast<const float4*>(Af + (size_t)gr * K + k0 + seg * 8 + 4);
        }
        va.x = pack2(f0.x, f0.y); va.y = pack2(f0.z, f0.w);
        va.z = pack2(f1.x, f1.y); va.w = pack2(f1.z, f1.w);
      } else {
        const uint* Au = (const uint*)Aptr;
        uint4 r4 = make_uint4(0, 0, 0, 0);
        if (gr < Mrows) r4 = *reinterpret_cast<const uint4*>(Au + (size_t)gr * (K >> 1) + ((k0 + seg * 8) >> 1));
        int c = k0 + seg * 8;
        uint uu[4] = {r4.x, r4.y, r4.z, r4.w};
#pragma unroll
        for (int q = 0; q < 4; q++) {
          float aa = fmaxf(bf_lo(uu[q]) * nAc[c + 2 * q] + nBc[c + 2 * q], 0.f);
          float bb = fmaxf(bf_hi(uu[q]) * nAc[c + 2 * q + 1] + nBc[c + 2 * q + 1], 0.f);
          uu[q] = pack2(aa, bb);
        }
        va = make_uint4(uu[0], uu[1], uu[2], uu[3]);
      }
      *reinterpret_cast<uint4*>(Ab + row * 256 + SWZ(row, seg * 16)) = va;
      uint4 vb = *reinterpret_cast<const uint4*>(Wt + (size_t)(c0 + row) * K + k0 + seg * 8);
      *reinterpret_cast<uint4*>(Bb + row * 256 + SWZ(row, seg * 16)) = vb;
    }
    __syncthreads();

#pragma unroll
    for (int ki = 0; ki < 4; ki++) {
      short8 a[2], b[8];
#pragma unroll
      for (int mi = 0; mi < 2; mi++) {
        int row = wi * 32 + mi * 16 + lr;
        a[mi] = *reinterpret_cast<const short8*>(Ab + row * 256 + SWZ(row, ki * 64 + kp * 16));
      }
#pragma unroll
      for (int ni = 0; ni < 8; ni++) {
        int row = ni * 16 + lr;
        b[ni] = *reinterpret_cast<const short8*>(Bb + row * 256 + SWZ(row, ki * 64 + kp * 16));
      }
#pragma unroll
      for (int mi = 0; mi < 2; mi++)
#pragma unroll
        for (int ni = 0; ni < 8; ni++)
          acc[mi][ni] = __builtin_amdgcn_mfma_f32_16x16x32_bf16(a[mi], b[ni], acc[mi][ni], 0, 0, 0);
    }
  }

  if (OMODE == 0) {
    float s_part[8], q_part[8];
#pragma unroll
    for (int ni = 0; ni < 8; ni++) { s_part[ni] = 0.f; q_part[ni] = 0.f; }
#pragma unroll
    for (int mi = 0; mi < 2; mi++) {
      int rbase = r0 + wi * 32 + mi * 16 + kp * 4;
#pragma unroll
      for (int ni = 0; ni < 8; ni++) {
        int gc = c0 + ni * 16 + lr;
        float bb = bias[col_off + gc];
#pragma unroll
        for (int j = 0; j < 4; j++) {
          int r = rbase + j;
          if (r < Mrows) {
            float yv = acc[mi][ni][j] + bb;
            ((ushort*)Yout)[(size_t)r * Nld + gc] = f2bf(yv);
            s_part[ni] += yv;
            q_part[ni] += yv * yv;
          }
        }
      }
    }
#pragma unroll
    for (int ni = 0; ni < 8; ni++) {
      s_part[ni] += __shfl_xor(s_part[ni], 16, 64);
      s_part[ni] += __shfl_xor(s_part[ni], 32, 64);
      q_part[ni] += __shfl_xor(q_part[ni], 16, 64);
      q_part[ni] += __shfl_xor(q_part[ni], 32, 64);
    }
    if (kp == 0) {
#pragma unroll
      for (int ni = 0; ni < 8; ni++) {
        sred[wi][ni * 16 + lr] = s_part[ni];
        qred[wi][ni * 16 + lr] = q_part[ni];
      }
    }
    __syncthreads();
    if (t < 128) {
      float S = sred[0][t] + sred[1][t] + sred[2][t] + sred[3][t];
      float Q = qred[0][t] + qred[1][t] + qred[2][t] + qred[3][t];
      atomicAdd(&gsum[c0 + t], S);
      atomicAdd(&gsq[c0 + t], Q);
    }
  } else {
#pragma unroll
    for (int mi = 0; mi < 2; mi++) {
      int rbase = r0 + wi * 32 + mi * 16 + kp * 4;
#pragma unroll
      for (int ni = 0; ni < 8; ni++) {
        int gc = c0 + ni * 16 + lr;
        if (gc < ncols) {
          float bb = bias[col_off + gc];
#pragma unroll
          for (int j = 0; j < 4; j++) {
            int r = rbase + j;
            if (r < Mrows) {
              float v = acc[mi][ni][j] + bb;
              ((float*)Yout)[(size_t)r * Nld + gc] = 1.0f / (1.0f + expf(-v));
            }
          }
        }
      }
    }
  }
}

__global__ void k_bnparams(const float* __restrict__ sum, const float* __restrict__ sumsq,
                           const float* __restrict__ gamma, const float* __restrict__ beta,
                           float* __restrict__ Ac, float* __restrict__ Bc,
                           int C, float invM) {
  int c = blockIdx.x * blockDim.x + threadIdx.x;
  if (c < C) {
    float mu = sum[c] * invM;
    float var = sumsq[c] * invM - mu * mu;
    float rs = rsqrtf(var + EPS_BN);
    float a = gamma[c] * rs;
    Ac[c] = a;
    Bc[c] = beta[c] - mu * a;
  }
}

// ---------------- graph readout (dense y): xg[g] = sum relu(y*A+B), sorted gids ----------------
__global__ __launch_bounds__(64) void k_readout(const uint* __restrict__ y,
                                                const int* __restrict__ gid,
                                                const float* __restrict__ Ac,
                                                const float* __restrict__ Bc,
                                                float* __restrict__ xg, int nNodes) {
  int l = threadIdx.x;
  int n0 = blockIdx.x * 64;
  int n1 = min(n0 + 64, nNodes);
  if (n0 >= nNodes) return;
  float A0 = Ac[2 * l], B0 = Bc[2 * l], A1 = Ac[2 * l + 1], B1 = Bc[2 * l + 1];
  float a0 = 0, a1 = 0;
  int cur = gid[n0];
  for (int n = n0; n < n1; n++) {
    int g = gid[n];
    if (g != cur) {
      atomicAdd(&xg[(size_t)cur * 128 + 2 * l], a0);
      atomicAdd(&xg[(size_t)cur * 128 + 2 * l + 1], a1);
      a0 = 0; a1 = 0; cur = g;
    }
    uint v = y[(size_t)n * 64 + l];
    a0 += fmaxf(bf_lo(v) * A0 + B0, 0.f);
    a1 += fmaxf(bf_hi(v) * A1 + B1, 0.f);
  }
  atomicAdd(&xg[(size_t)cur * 128 + 2 * l], a0);
  atomicAdd(&xg[(size_t)cur * 128 + 2 * l + 1], a1);
}

extern "C" void kernel_launch(void* const* d_in, const int* in_sizes, int n_in,
                              void* d_out, int out_size, void* d_ws, size_t ws_size,
                              hipStream_t stream) {
  const float* h    = (const float*)d_in[0];
  const int*   esrc = (const int*)d_in[1];
  const int*   edst = (const int*)d_in[2];
  const int*   gid  = (const int*)d_in[3];
  const float* W1   = (const float*)d_in[4];
  const float* b1   = (const float*)d_in[5];
  const float* g1g  = (const float*)d_in[6];
  const float* g1b  = (const float*)d_in[7];
  const float* Wg   = (const float*)d_in[8];
  const float* bg   = (const float*)d_in[9];
  const float* gg   = (const float*)d_in[10];
  const float* gb   = (const float*)d_in[11];
  const float* fc1W = (const float*)d_in[12];
  const float* fc1b = (const float*)d_in[13];
  const float* bn1g = (const float*)d_in[14];
  const float* bn1b = (const float*)d_in[15];
  const float* linW = (const float*)d_in[16];
  const float* linb = (const float*)d_in[17];
  const float* lbng = (const float*)d_in[18];
  const float* lbnb = (const float*)d_in[19];
  const float* fc2W = (const float*)d_in[20];
  const float* fc2b = (const float*)d_in[21];
  float* out = (float*)d_out;

  char* p = (char*)d_ws;
  auto alloc = [&](size_t bytes) {
    char* q = p;
    p += (bytes + 255) & ~(size_t)255;
    return q;
  };
  int* row_ptr = (int*)alloc((N_NODES + 1) * sizeof(int));
  int* bcnt    = (int*)alloc(NBUCK * sizeof(int));
  int* bbase   = (int*)alloc((NBUCK + 1) * sizeof(int));
  int* bcur    = (int*)alloc(NBUCK * sizeof(int));
  int* csr     = (int*)alloc(N_EDGES * sizeof(int));
  uint* hb     = (uint*)alloc((size_t)N_NODES * 64 * sizeof(uint));
  uint* yA     = (uint*)alloc((size_t)N_NODES * 64 * sizeof(uint));
  uint* yB     = (uint*)alloc((size_t)N_NODES * 64 * sizeof(uint));
  ushort* Wt   = (ushort*)alloc(5 * 128 * 128 * sizeof(ushort));
  ushort* fc1Wt = (ushort*)alloc(512 * 128 * sizeof(ushort));
  ushort* linWt = (ushort*)alloc(256 * 512 * sizeof(ushort));
  ushort* fc2Wt = (ushort*)alloc(256 * 256 * sizeof(ushort));
  float* ssum  = (float*)alloc(512 * sizeof(float));
  float* ssq   = (float*)alloc(512 * sizeof(float));
  float* Ac    = (float*)alloc(512 * sizeof(float));
  float* Bc    = (float*)alloc(512 * sizeof(float));
  float* xg    = (float*)alloc((size_t)N_GRAPHS * 128 * sizeof(float));
  uint* y1b    = (uint*)alloc((size_t)N_GRAPHS * 256 * sizeof(uint));
  uint* y2b    = (uint*)alloc((size_t)N_GRAPHS * 128 * sizeof(uint));
  // staging for binned scatter aliases yB (first written at layer 1, after CSR build)
  uint2* staging = (uint2*)yB;  // 12.8 MB <= 25.6 MB

  // ---- prep: conversions + CSR build ----
  k_conv_h<<<(N_NODES * 64 + 255) / 256, 256, 0, stream>>>(h, hb, N_NODES);
  k_prep_wt<<<64, 256, 0, stream>>>(W1, Wt, 78);
  for (int l = 0; l < 4; l++)
    k_prep_wt<<<64, 256, 0, stream>>>(Wg + (size_t)l * 128 * 128, Wt + (size_t)(l + 1) * 128 * 128, 128);
  k_prep_wt_gen<<<(512 * 128 + 255) / 256, 256, 0, stream>>>(fc1W, 512, 0, 512, 128, fc1Wt, 512 * 128);
  k_prep_wt_gen<<<(256 * 512 + 255) / 256, 256, 0, stream>>>(linW, 256, 0, 256, 512, linWt, 256 * 512);
  k_prep_wt_gen<<<(256 * 256 + 255) / 256, 256, 0, stream>>>(fc2W, 408, 204, 204, 256, fc2Wt, 256 * 256);

  hipMemsetAsync(bcnt, 0, NBUCK * sizeof(int), stream);
  k_bin_count<<<(N_EDGES + BIN_CHUNK - 1) / BIN_CHUNK, 256, 0, stream>>>(edst, bcnt, N_EDGES);
  k_bucket_scan<<<1, 512, 0, stream>>>(bcnt, bbase, bcur);
  k_bin<<<(N_EDGES + BIN_CHUNK - 1) / BIN_CHUNK, 256, 0, stream>>>(esrc, edst, bcur,
                                                                   staging, N_EDGES);
  k_place2<<<NBUCK, 256, 0, stream>>>(staging, bbase, row_ptr, csr, N_NODES, N_EDGES);

  const float invN = 1.0f / (float)N_NODES;
  const float invG = 1.0f / (float)N_GRAPHS;
  const int GIN_GRID = (N_NODES + 127) / 128;

  // ---- 5 fused GIN layers (ping-pong yA/yB; layer 0 reads hb) ----
  const uint* Xin = hb;
  uint* Yout = yA;
  for (int layer = 0; layer < 5; layer++) {
    const ushort* Wl = Wt + (size_t)layer * 128 * 128;
    const float* bl  = (layer == 0) ? b1 : bg + (size_t)(layer - 1) * 128;
    const float* gl  = (layer == 0) ? g1g : gg + (size_t)(layer - 1) * 128;
    const float* bl2 = (layer == 0) ? g1b : gb + (size_t)(layer - 1) * 128;

    hipMemsetAsync(ssum, 0, 128 * sizeof(float), stream);
    hipMemsetAsync(ssq, 0, 128 * sizeof(float), stream);
    if (layer == 0)
      k_gin_fused<false><<<GIN_GRID, 256, 0, stream>>>(Xin, row_ptr, csr, Wl, bl, 2.0f,
                                                       nullptr, nullptr, (ushort*)Yout,
                                                       N_NODES, ssum, ssq);
    else
      k_gin_fused<true><<<GIN_GRID, 256, 0, stream>>>(Xin, row_ptr, csr, Wl, bl, 2.0f,
                                                      Ac, Bc, (ushort*)Yout,
                                                      N_NODES, ssum, ssq);
    k_bnparams<<<1, 128, 0, stream>>>(ssum, ssq, gl, bl2, Ac, Bc, 128, invN);
    Xin = Yout;
    Yout = (Yout == yA) ? yB : yA;
  }
  const uint* yfin = Xin;  // layer-5 pre-norm output (yA)

  // ---- readout (applies layer-5 BN+ReLU inline) ----
  hipMemsetAsync(xg, 0, (size_t)N_GRAPHS * 128 * sizeof(float), stream);
  k_readout<<<(N_NODES + 63) / 64, 64, 0, stream>>>(yfin, gid, Ac, Bc, xg, N_NODES);

  // ---- fc1 (128 -> 512): fp32 A, fused stats ----
  hipMemsetAsync(ssum, 0, 512 * sizeof(float), stream);
  hipMemsetAsync(ssq, 0, 512 * sizeof(float), stream);
  k_head_mfma<0, 0><<<dim3(4, 16), 256, 0, stream>>>(xg, N_GRAPHS, 128, fc1Wt, fc1b, 0, 512,
                                                     nullptr, nullptr, y1b, 512, ssum, ssq);
  k_bnparams<<<1, 512, 0, stream>>>(ssum, ssq, bn1g, bn1b, Ac, Bc, 512, invG);

  // ---- lin (512 -> 256): bf16 A + inline bn1/relu, fused stats ----
  hipMemsetAsync(ssum, 0, 256 * sizeof(float), stream);
  hipMemsetAsync(ssq, 0, 256 * sizeof(float), stream);
  k_head_mfma<1, 0><<<dim3(2, 16), 256, 0, stream>>>(y1b, N_GRAPHS, 512, linWt, linb, 0, 256,
                                                     Ac, Bc, y2b, 256, ssum, ssq);
  k_bnparams<<<1, 256, 0, stream>>>(ssum, ssq, lbng, lbnb, Ac, Bc, 256, invG);

  // ---- fc2 (256 -> 204): bf16 A + inline lbn/relu, sigmoid, write out ----
  k_head_mfma<1, 1><<<dim3(2, 16), 256, 0, stream>>>(y2b, N_GRAPHS, 256, fc2Wt, fc2b, 204, NCLS,
                                                     Ac, Bc, out, NCLS, nullptr, nullptr);
}

// Round 8
// 651.620 us; speedup vs baseline: 2.3586x; 1.8439x over previous
//
#include <hip/hip_runtime.h>
#include <hip/hip_bf16.h>
#include <math.h>

#define N_NODES 100000
#define N_EDGES 1600000
#define N_GRAPHS 2048
#define NCLS 204
#define EPS_BN 1e-5f
#define NBUCK ((N_NODES + 255) / 256)   // 391
#define BIN_CHUNK 8192

typedef __attribute__((ext_vector_type(8))) short short8;
typedef __attribute__((ext_vector_type(4))) float f32x4;

__device__ __forceinline__ float bf_lo(uint v) { union { uint i; float f; } c; c.i = v << 16; return c.f; }
__device__ __forceinline__ float bf_hi(uint v) { union { uint i; float f; } c; c.i = v & 0xffff0000u; return c.f; }
__device__ __forceinline__ ushort f2bf(float v) {
  __hip_bfloat16 b = __float2bfloat16(v);
  return *reinterpret_cast<ushort*>(&b);
}
__device__ __forceinline__ uint pack2(float a, float b) {
  return (uint)f2bf(a) | ((uint)f2bf(b) << 16);
}

// ---------------- CSR build (binned, no per-node atomics; 4B packed staging) ----------------
__global__ __launch_bounds__(256) void k_bin_count(const int* __restrict__ dst,
                                                   int* __restrict__ bcnt, int E) {
  __shared__ int hist[NBUCK];
  int t = threadIdx.x;
  int e0 = blockIdx.x * BIN_CHUNK;
  for (int b = t; b < NBUCK; b += 256) hist[b] = 0;
  __syncthreads();
  for (int e = e0 + t; e < min(e0 + BIN_CHUNK, E); e += 256)
    atomicAdd(&hist[dst[e] >> 8], 1);
  __syncthreads();
  for (int b = t; b < NBUCK; b += 256)
    if (hist[b] > 0) atomicAdd(&bcnt[b], hist[b]);
}

__global__ __launch_bounds__(512) void k_bucket_scan(const int* __restrict__ bcnt,
                                                     int* __restrict__ bbase,
                                                     int* __restrict__ bcur) {
  __shared__ int sh[512];
  int t = threadIdx.x;
  int v = (t < NBUCK) ? bcnt[t] : 0;
  sh[t] = v;
  __syncthreads();
  for (int d = 1; d < 512; d <<= 1) {
    int x = (t >= d) ? sh[t - d] : 0;
    __syncthreads();
    sh[t] += x;
    __syncthreads();
  }
  if (t < NBUCK) {
    bbase[t + 1] = sh[t];
    bcur[t] = sh[t] - v;
    if (t == 0) bbase[0] = 0;
  }
}

// staging entry: src (24b) | local_dst (8b)
__global__ __launch_bounds__(256) void k_bin(const int* __restrict__ src,
                                             const int* __restrict__ dst,
                                             int* __restrict__ cursor,
                                             uint* __restrict__ staging, int E) {
  __shared__ int hist[NBUCK];
  __shared__ int base_s[NBUCK];
  int t = threadIdx.x;
  int e0 = blockIdx.x * BIN_CHUNK;
  for (int b = t; b < NBUCK; b += 256) hist[b] = 0;
  __syncthreads();
  for (int e = e0 + t; e < min(e0 + BIN_CHUNK, E); e += 256)
    atomicAdd(&hist[dst[e] >> 8], 1);
  __syncthreads();
  for (int b = t; b < NBUCK; b += 256) {
    int hh = hist[b];
    if (hh > 0) base_s[b] = atomicAdd(&cursor[b], hh);
    hist[b] = 0;
  }
  __syncthreads();
  for (int e = e0 + t; e < min(e0 + BIN_CHUNK, E); e += 256) {
    int d = dst[e];
    int b = d >> 8;
    int r = atomicAdd(&hist[b], 1);
    staging[base_s[b] + r] = (uint)src[e] | ((uint)(d & 255) << 24);
  }
}

__global__ __launch_bounds__(256) void k_place2(const uint* __restrict__ staging,
                                                const int* __restrict__ bbase,
                                                int* __restrict__ row_ptr,
                                                int* __restrict__ csr, int nNodes, int E) {
  __shared__ int cnt[256];
  __shared__ int scn[256];
  __shared__ int cur[256];
  int t = threadIdx.x;
  int b = blockIdx.x;
  int n0 = b * 256;
  cnt[t] = 0;
  __syncthreads();
  int s = bbase[b], e = bbase[b + 1];
  for (int i = s + t; i < e; i += 256) atomicAdd(&cnt[staging[i] >> 24], 1);
  __syncthreads();
  int v = cnt[t];
  scn[t] = v;
  __syncthreads();
  for (int d = 1; d < 256; d <<= 1) {
    int x = (t >= d) ? scn[t - d] : 0;
    __syncthreads();
    scn[t] += x;
    __syncthreads();
  }
  int excl = scn[t] - v;
  if (n0 + t < nNodes) row_ptr[n0 + t] = s + excl;
  cur[t] = s + excl;
  __syncthreads();
  for (int i = s + t; i < e; i += 256) {
    uint ed = staging[i];
    int pos = atomicAdd(&cur[ed >> 24], 1);
    csr[pos] = (int)(ed & 0xFFFFFF);
  }
  if (b == 0 && t == 0) row_ptr[nNodes] = E;
}

// ---------------- conversions / weight prep ----------------
__global__ void k_conv_h(const float* __restrict__ h, uint* __restrict__ hb, int nNodes) {
  int i = blockIdx.x * blockDim.x + threadIdx.x;
  if (i < nNodes * 64) {
    int n = i >> 6, cp = i & 63;
    int c = cp * 2;
    float a = (c < 78) ? h[(size_t)n * 78 + c] : 0.0f;
    float b = (c + 1 < 78) ? h[(size_t)n * 78 + c + 1] : 0.0f;
    hb[i] = pack2(a, b);
  }
}

// all 5 node-layer weights in one launch: layer = blockIdx.y
__global__ void k_prep_wt_all(const float* __restrict__ W1, const float* __restrict__ Wg,
                              ushort* __restrict__ Wt) {
  int i = blockIdx.x * blockDim.x + threadIdx.x;
  int layer = blockIdx.y;
  if (i < 128 * 128) {
    int n = i >> 7, k = i & 127;
    const float* W = (layer == 0) ? W1 : Wg + (size_t)(layer - 1) * 128 * 128;
    int K = (layer == 0) ? 78 : 128;
    float v = (k < K) ? W[(size_t)k * 128 + n] : 0.0f;
    Wt[(size_t)layer * 128 * 128 + i] = f2bf(v);
  }
}

__global__ void k_prep_wt_gen(const float* __restrict__ W, int wld, int col_off, int nkeep,
                              int K, ushort* __restrict__ Wt, int total) {
  int i = blockIdx.x * blockDim.x + threadIdx.x;
  if (i < total) {
    int n = i / K, k = i - n * K;
    float v = (n < nkeep) ? W[(size_t)k * wld + col_off + n] : 0.0f;
    Wt[i] = f2bf(v);
  }
}

// ---------------- GIN aggregation, inline prev-layer BN params from raw stats ----------------
template <bool NRM>
__global__ __launch_bounds__(256) void k_agg_f(const uint* __restrict__ y,
                                               const int* __restrict__ row_ptr,
                                               const int* __restrict__ csr,
                                               const float* __restrict__ psum,
                                               const float* __restrict__ psq,
                                               const float* __restrict__ pgamma,
                                               const float* __restrict__ pbeta,
                                               float invM,
                                               uint* __restrict__ M, int nNodes) {
  int n = blockIdx.x * 4 + (threadIdx.x >> 6);
  if (n >= nNodes) return;
  int l = threadIdx.x & 63;
  float A0 = 1.f, B0 = 0.f, A1 = 1.f, B1 = 0.f;
  if (NRM) {
    int c0 = 2 * l, c1 = 2 * l + 1;
    float mu0 = psum[c0] * invM;
    float va0 = psq[c0] * invM - mu0 * mu0;
    A0 = pgamma[c0] * rsqrtf(va0 + EPS_BN);
    B0 = pbeta[c0] - mu0 * A0;
    float mu1 = psum[c1] * invM;
    float va1 = psq[c1] * invM - mu1 * mu1;
    A1 = pgamma[c1] * rsqrtf(va1 + EPS_BN);
    B1 = pbeta[c1] - mu1 * A1;
  }
  auto flo = [&](uint v) { float x = bf_lo(v); return NRM ? fmaxf(x * A0 + B0, 0.f) : x; };
  auto fhi = [&](uint v) { float x = bf_hi(v); return NRM ? fmaxf(x * A1 + B1, 0.f) : x; };

  uint self = y[(size_t)n * 64 + l];
  float a0 = 2.0f * flo(self);
  float a1 = 2.0f * fhi(self);
  int s = row_ptr[n], e = row_ptr[n + 1];

  for (int base = s; base < e; base += 64) {
    int cnt = e - base;
    if (cnt > 64) cnt = 64;
    int myidx = (base + l < e) ? csr[base + l] : 0;
    int j = 0;
    for (; j + 4 <= cnt; j += 4) {
      int i0 = __shfl(myidx, j);
      int i1 = __shfl(myidx, j + 1);
      int i2 = __shfl(myidx, j + 2);
      int i3 = __shfl(myidx, j + 3);
      uint v0 = y[(size_t)i0 * 64 + l];
      uint v1 = y[(size_t)i1 * 64 + l];
      uint v2 = y[(size_t)i2 * 64 + l];
      uint v3 = y[(size_t)i3 * 64 + l];
      a0 += flo(v0) + flo(v1) + flo(v2) + flo(v3);
      a1 += fhi(v0) + fhi(v1) + fhi(v2) + fhi(v3);
    }
    for (; j < cnt; j++) {
      int i0 = __shfl(myidx, j);
      uint v = y[(size_t)i0 * 64 + l];
      a0 += flo(v);
      a1 += fhi(v);
    }
  }
  M[(size_t)n * 64 + l] = pack2(a0, a1);
}

// ---------------- node-layer MFMA GEMM + fused BN stats ----------------
#define SWZ(row, boff) ((boff) ^ (((row) & 7) << 4))
__global__ __launch_bounds__(256) void k_gemm_mfma(const ushort* __restrict__ A,
                                                   const ushort* __restrict__ Wt,
                                                   const float* __restrict__ bias, float bscale,
                                                   ushort* __restrict__ Y, int Mrows,
                                                   float* __restrict__ gsum,
                                                   float* __restrict__ gsq) {
  __shared__ ushort As[128 * 128];
  __shared__ ushort Bs[128 * 128];
  __shared__ float sred[4][128], qred[4][128];
  int t = threadIdx.x;
  int r0 = blockIdx.x * 128;
  char* Ab = (char*)As;
  char* Bb = (char*)Bs;

  for (int it = 0; it < 8; it++) {
    int e = it * 256 + t;
    int row = e >> 4, seg = e & 15;
    uint4 va = make_uint4(0, 0, 0, 0);
    int gr = r0 + row;
    if (gr < Mrows) va = *reinterpret_cast<const uint4*>(A + (size_t)gr * 128 + seg * 8);
    *reinterpret_cast<uint4*>(Ab + row * 256 + SWZ(row, seg * 16)) = va;
    uint4 vb = *reinterpret_cast<const uint4*>(Wt + (size_t)row * 128 + seg * 8);
    *reinterpret_cast<uint4*>(Bb + row * 256 + SWZ(row, seg * 16)) = vb;
  }
  __syncthreads();

  int wi = t >> 6;
  int l = t & 63;
  int lr = l & 15;
  int kp = l >> 4;

  f32x4 acc[2][8];
#pragma unroll
  for (int mi = 0; mi < 2; mi++)
#pragma unroll
    for (int ni = 0; ni < 8; ni++) acc[mi][ni] = (f32x4){0.f, 0.f, 0.f, 0.f};

#pragma unroll
  for (int ki = 0; ki < 4; ki++) {
    short8 a[2], b[8];
#pragma unroll
    for (int mi = 0; mi < 2; mi++) {
      int row = wi * 32 + mi * 16 + lr;
      a[mi] = *reinterpret_cast<const short8*>(Ab + row * 256 + SWZ(row, ki * 64 + kp * 16));
    }
#pragma unroll
    for (int ni = 0; ni < 8; ni++) {
      int row = ni * 16 + lr;
      b[ni] = *reinterpret_cast<const short8*>(Bb + row * 256 + SWZ(row, ki * 64 + kp * 16));
    }
#pragma unroll
    for (int mi = 0; mi < 2; mi++)
#pragma unroll
      for (int ni = 0; ni < 8; ni++)
        acc[mi][ni] = __builtin_amdgcn_mfma_f32_16x16x32_bf16(a[mi], b[ni], acc[mi][ni], 0, 0, 0);
  }

  float s_part[8], q_part[8];
#pragma unroll
  for (int ni = 0; ni < 8; ni++) { s_part[ni] = 0.f; q_part[ni] = 0.f; }

#pragma unroll
  for (int mi = 0; mi < 2; mi++) {
    int rbase = r0 + wi * 32 + mi * 16 + kp * 4;
#pragma unroll
    for (int ni = 0; ni < 8; ni++) {
      int col = ni * 16 + lr;
      float bb = bscale * bias[col];
#pragma unroll
      for (int j = 0; j < 4; j++) {
        int r = rbase + j;
        if (r < Mrows) {
          float yv = acc[mi][ni][j] + bb;
          Y[(size_t)r * 128 + col] = f2bf(yv);
          s_part[ni] += yv;
          q_part[ni] += yv * yv;
        }
      }
    }
  }

#pragma unroll
  for (int ni = 0; ni < 8; ni++) {
    s_part[ni] += __shfl_xor(s_part[ni], 16, 64);
    s_part[ni] += __shfl_xor(s_part[ni], 32, 64);
    q_part[ni] += __shfl_xor(q_part[ni], 16, 64);
    q_part[ni] += __shfl_xor(q_part[ni], 32, 64);
  }
  if (kp == 0) {
#pragma unroll
    for (int ni = 0; ni < 8; ni++) {
      sred[wi][ni * 16 + lr] = s_part[ni];
      qred[wi][ni * 16 + lr] = q_part[ni];
    }
  }
  __syncthreads();
  if (t < 128) {
    float S = sred[0][t] + sred[1][t] + sred[2][t] + sred[3][t];
    float Q = qred[0][t] + qred[1][t] + qred[2][t] + qred[3][t];
    atomicAdd(&gsum[t], S);
    atomicAdd(&gsq[t], Q);
  }
}

// ---------------- head MFMA GEMM ----------------
template <int AMODE, int OMODE>
__global__ __launch_bounds__(256) void k_head_mfma(const void* __restrict__ Aptr,
                                                   int Mrows, int K,
                                                   const ushort* __restrict__ Wt,
                                                   const float* __restrict__ bias,
                                                   int col_off, int ncols,
                                                   const float* __restrict__ nAc,
                                                   const float* __restrict__ nBc,
                                                   void* __restrict__ Yout, int Nld,
                                                   float* __restrict__ gsum,
                                                   float* __restrict__ gsq) {
  __shared__ ushort As[128 * 128];
  __shared__ ushort Bs[128 * 128];
  __shared__ float sred[4][128], qred[4][128];
  int t = threadIdx.x;
  int r0 = blockIdx.y * 128;
  int c0 = blockIdx.x * 128;
  char* Ab = (char*)As;
  char* Bb = (char*)Bs;

  int wi = t >> 6;
  int l = t & 63;
  int lr = l & 15;
  int kp = l >> 4;

  f32x4 acc[2][8];
#pragma unroll
  for (int mi = 0; mi < 2; mi++)
#pragma unroll
    for (int ni = 0; ni < 8; ni++) acc[mi][ni] = (f32x4){0.f, 0.f, 0.f, 0.f};

  for (int k0 = 0; k0 < K; k0 += 128) {
    if (k0) __syncthreads();
    for (int it = 0; it < 8; it++) {
      int e = it * 256 + t;
      int row = e >> 4, seg = e & 15;
      int gr = r0 + row;
      uint4 va;
      if (AMODE == 0) {
        const float* Af = (const float*)Aptr;
        float4 f0 = {0.f, 0.f, 0.f, 0.f}, f1 = {0.f, 0.f, 0.f, 0.f};
        if (gr < Mrows) {
          f0 = *reinterpret_cast<const float4*>(Af + (size_t)gr * K + k0 + seg * 8);
          f1 = *reinterpret_cast<const float4*>(Af + (size_t)gr * K + k0 + seg * 8 + 4);
        }
        va.x = pack2(f0.x, f0.y); va.y = pack2(f0.z, f0.w);
        va.z = pack2(f1.x, f1.y); va.w = pack2(f1.z, f1.w);
      } else {
        const uint* Au = (const uint*)Aptr;
        uint4 r4 = make_uint4(0, 0, 0, 0);
        if (gr < Mrows) r4 = *reinterpret_cast<const uint4*>(Au + (size_t)gr * (K >> 1) + ((k0 + seg * 8) >> 1));
        int c = k0 + seg * 8;
        uint uu[4] = {r4.x, r4.y, r4.z, r4.w};
#pragma unroll
        for (int q = 0; q < 4; q++) {
          float aa = fmaxf(bf_lo(uu[q]) * nAc[c + 2 * q] + nBc[c + 2 * q], 0.f);
          float bb = fmaxf(bf_hi(uu[q]) * nAc[c + 2 * q + 1] + nBc[c + 2 * q + 1], 0.f);
          uu[q] = pack2(aa, bb);
        }
        va = make_uint4(uu[0], uu[1], uu[2], uu[3]);
      }
      *reinterpret_cast<uint4*>(Ab + row * 256 + SWZ(row, seg * 16)) = va;
      uint4 vb = *reinterpret_cast<const uint4*>(Wt + (size_t)(c0 + row) * K + k0 + seg * 8);
      *reinterpret_cast<uint4*>(Bb + row * 256 + SWZ(row, seg * 16)) = vb;
    }
    __syncthreads();

#pragma unroll
    for (int ki = 0; ki < 4; ki++) {
      short8 a[2], b[8];
#pragma unroll
      for (int mi = 0; mi < 2; mi++) {
        int row = wi * 32 + mi * 16 + lr;
        a[mi] = *reinterpret_cast<const short8*>(Ab + row * 256 + SWZ(row, ki * 64 + kp * 16));
      }
#pragma unroll
      for (int ni = 0; ni < 8; ni++) {
        int row = ni * 16 + lr;
        b[ni] = *reinterpret_cast<const short8*>(Bb + row * 256 + SWZ(row, ki * 64 + kp * 16));
      }
#pragma unroll
      for (int mi = 0; mi < 2; mi++)
#pragma unroll
        for (int ni = 0; ni < 8; ni++)
          acc[mi][ni] = __builtin_amdgcn_mfma_f32_16x16x32_bf16(a[mi], b[ni], acc[mi][ni], 0, 0, 0);
    }
  }

  if (OMODE == 0) {
    float s_part[8], q_part[8];
#pragma unroll
    for (int ni = 0; ni < 8; ni++) { s_part[ni] = 0.f; q_part[ni] = 0.f; }
#pragma unroll
    for (int mi = 0; mi < 2; mi++) {
      int rbase = r0 + wi * 32 + mi * 16 + kp * 4;
#pragma unroll
      for (int ni = 0; ni < 8; ni++) {
        int gc = c0 + ni * 16 + lr;
        float bb = bias[col_off + gc];
#pragma unroll
        for (int j = 0; j < 4; j++) {
          int r = rbase + j;
          if (r < Mrows) {
            float yv = acc[mi][ni][j] + bb;
            ((ushort*)Yout)[(size_t)r * Nld + gc] = f2bf(yv);
            s_part[ni] += yv;
            q_part[ni] += yv * yv;
          }
        }
      }
    }
#pragma unroll
    for (int ni = 0; ni < 8; ni++) {
      s_part[ni] += __shfl_xor(s_part[ni], 16, 64);
      s_part[ni] += __shfl_xor(s_part[ni], 32, 64);
      q_part[ni] += __shfl_xor(q_part[ni], 16, 64);
      q_part[ni] += __shfl_xor(q_part[ni], 32, 64);
    }
    if (kp == 0) {
#pragma unroll
      for (int ni = 0; ni < 8; ni++) {
        sred[wi][ni * 16 + lr] = s_part[ni];
        qred[wi][ni * 16 + lr] = q_part[ni];
      }
    }
    __syncthreads();
    if (t < 128) {
      float S = sred[0][t] + sred[1][t] + sred[2][t] + sred[3][t];
      float Q = qred[0][t] + qred[1][t] + qred[2][t] + qred[3][t];
      atomicAdd(&gsum[c0 + t], S);
      atomicAdd(&gsq[c0 + t], Q);
    }
  } else {
#pragma unroll
    for (int mi = 0; mi < 2; mi++) {
      int rbase = r0 + wi * 32 + mi * 16 + kp * 4;
#pragma unroll
      for (int ni = 0; ni < 8; ni++) {
        int gc = c0 + ni * 16 + lr;
        if (gc < ncols) {
          float bb = bias[col_off + gc];
#pragma unroll
          for (int j = 0; j < 4; j++) {
            int r = rbase + j;
            if (r < Mrows) {
              float v = acc[mi][ni][j] + bb;
              ((float*)Yout)[(size_t)r * Nld + gc] = 1.0f / (1.0f + expf(-v));
            }
          }
        }
      }
    }
  }
}

__global__ void k_bnparams(const float* __restrict__ sum, const float* __restrict__ sumsq,
                           const float* __restrict__ gamma, const float* __restrict__ beta,
                           float* __restrict__ Ac, float* __restrict__ Bc,
                           int C, float invM) {
  int c = blockIdx.x * blockDim.x + threadIdx.x;
  if (c < C) {
    float mu = sum[c] * invM;
    float var = sumsq[c] * invM - mu * mu;
    float rs = rsqrtf(var + EPS_BN);
    float a = gamma[c] * rs;
    Ac[c] = a;
    Bc[c] = beta[c] - mu * a;
  }
}

// ---------------- graph readout: xg[g] = sum relu(y*A+B), inline BN params ----------------
__global__ __launch_bounds__(64) void k_readout(const uint* __restrict__ y,
                                                const int* __restrict__ gid,
                                                const float* __restrict__ psum,
                                                const float* __restrict__ psq,
                                                const float* __restrict__ pgamma,
                                                const float* __restrict__ pbeta,
                                                float invM,
                                                float* __restrict__ xg, int nNodes) {
  int l = threadIdx.x;
  int n0 = blockIdx.x * 64;
  int n1 = min(n0 + 64, nNodes);
  if (n0 >= nNodes) return;
  int c0 = 2 * l, c1 = 2 * l + 1;
  float mu0 = psum[c0] * invM;
  float va0 = psq[c0] * invM - mu0 * mu0;
  float A0 = pgamma[c0] * rsqrtf(va0 + EPS_BN);
  float B0 = pbeta[c0] - mu0 * A0;
  float mu1 = psum[c1] * invM;
  float va1 = psq[c1] * invM - mu1 * mu1;
  float A1 = pgamma[c1] * rsqrtf(va1 + EPS_BN);
  float B1 = pbeta[c1] - mu1 * A1;
  float a0 = 0, a1 = 0;
  int cur = gid[n0];
  for (int n = n0; n < n1; n++) {
    int g = gid[n];
    if (g != cur) {
      atomicAdd(&xg[(size_t)cur * 128 + 2 * l], a0);
      atomicAdd(&xg[(size_t)cur * 128 + 2 * l + 1], a1);
      a0 = 0; a1 = 0; cur = g;
    }
    uint v = y[(size_t)n * 64 + l];
    a0 += fmaxf(bf_lo(v) * A0 + B0, 0.f);
    a1 += fmaxf(bf_hi(v) * A1 + B1, 0.f);
  }
  atomicAdd(&xg[(size_t)cur * 128 + 2 * l], a0);
  atomicAdd(&xg[(size_t)cur * 128 + 2 * l + 1], a1);
}

extern "C" void kernel_launch(void* const* d_in, const int* in_sizes, int n_in,
                              void* d_out, int out_size, void* d_ws, size_t ws_size,
                              hipStream_t stream) {
  const float* h    = (const float*)d_in[0];
  const int*   esrc = (const int*)d_in[1];
  const int*   edst = (const int*)d_in[2];
  const int*   gid  = (const int*)d_in[3];
  const float* W1   = (const float*)d_in[4];
  const float* b1   = (const float*)d_in[5];
  const float* g1g  = (const float*)d_in[6];
  const float* g1b  = (const float*)d_in[7];
  const float* Wg   = (const float*)d_in[8];
  const float* bg   = (const float*)d_in[9];
  const float* gg   = (const float*)d_in[10];
  const float* gb   = (const float*)d_in[11];
  const float* fc1W = (const float*)d_in[12];
  const float* fc1b = (const float*)d_in[13];
  const float* bn1g = (const float*)d_in[14];
  const float* bn1b = (const float*)d_in[15];
  const float* linW = (const float*)d_in[16];
  const float* linb = (const float*)d_in[17];
  const float* lbng = (const float*)d_in[18];
  const float* lbnb = (const float*)d_in[19];
  const float* fc2W = (const float*)d_in[20];
  const float* fc2b = (const float*)d_in[21];
  float* out = (float*)d_out;

  char* p = (char*)d_ws;
  auto alloc = [&](size_t bytes) {
    char* q = p;
    p += (bytes + 255) & ~(size_t)255;
    return q;
  };
  int* row_ptr = (int*)alloc((N_NODES + 1) * sizeof(int));
  int* bcnt    = (int*)alloc(NBUCK * sizeof(int));
  int* bbase   = (int*)alloc((NBUCK + 1) * sizeof(int));
  int* bcur    = (int*)alloc(NBUCK * sizeof(int));
  int* csr     = (int*)alloc(N_EDGES * sizeof(int));
  uint* hb     = (uint*)alloc((size_t)N_NODES * 64 * sizeof(uint));
  uint* Mb     = (uint*)alloc((size_t)N_NODES * 64 * sizeof(uint));
  uint* yb     = (uint*)alloc((size_t)N_NODES * 64 * sizeof(uint));
  ushort* Wt   = (ushort*)alloc(5 * 128 * 128 * sizeof(ushort));
  ushort* fc1Wt = (ushort*)alloc(512 * 128 * sizeof(ushort));
  ushort* linWt = (ushort*)alloc(256 * 512 * sizeof(ushort));
  ushort* fc2Wt = (ushort*)alloc(256 * 256 * sizeof(ushort));
  // stats arena: 5 layers x (128 sum + 128 sq) + fc1 (512+512) + lin (256+256)
  float* stats = (float*)alloc(2816 * sizeof(float));
  float* Ac    = (float*)alloc(512 * sizeof(float));
  float* Bc    = (float*)alloc(512 * sizeof(float));
  float* xg    = (float*)alloc((size_t)N_GRAPHS * 128 * sizeof(float));
  uint* y1b    = (uint*)alloc((size_t)N_GRAPHS * 256 * sizeof(uint));
  uint* y2b    = (uint*)alloc((size_t)N_GRAPHS * 128 * sizeof(uint));
  uint* staging = (uint*)Mb;  // 6.4 MB aliases Mb (dead until layer loop)

  float* lsum = stats;                 // [layer]*256
  float* fsum1 = stats + 1280;         // 512
  float* fsq1  = stats + 1792;         // 512
  float* lsum2 = stats + 2304;         // 256
  float* lsq2  = stats + 2560;         // 256

  // ---- prep: conversions + weights ----
  k_conv_h<<<(N_NODES * 64 + 255) / 256, 256, 0, stream>>>(h, hb, N_NODES);
  {
    dim3 g(64, 5);
    k_prep_wt_all<<<g, 256, 0, stream>>>(W1, Wg, Wt);
  }
  k_prep_wt_gen<<<(512 * 128 + 255) / 256, 256, 0, stream>>>(fc1W, 512, 0, 512, 128, fc1Wt, 512 * 128);
  k_prep_wt_gen<<<(256 * 512 + 255) / 256, 256, 0, stream>>>(linW, 256, 0, 256, 512, linWt, 256 * 512);
  k_prep_wt_gen<<<(256 * 256 + 255) / 256, 256, 0, stream>>>(fc2W, 408, 204, 204, 256, fc2Wt, 256 * 256);

  // ---- stats arena + xg clear (one shot) ----
  hipMemsetAsync(stats, 0, 2816 * sizeof(float), stream);
  hipMemsetAsync(xg, 0, (size_t)N_GRAPHS * 128 * sizeof(float), stream);

  // ---- CSR build ----
  hipMemsetAsync(bcnt, 0, NBUCK * sizeof(int), stream);
  k_bin_count<<<(N_EDGES + BIN_CHUNK - 1) / BIN_CHUNK, 256, 0, stream>>>(edst, bcnt, N_EDGES);
  k_bucket_scan<<<1, 512, 0, stream>>>(bcnt, bbase, bcur);
  k_bin<<<(N_EDGES + BIN_CHUNK - 1) / BIN_CHUNK, 256, 0, stream>>>(esrc, edst, bcur,
                                                                   staging, N_EDGES);
  k_place2<<<NBUCK, 256, 0, stream>>>(staging, bbase, row_ptr, csr, N_NODES, N_EDGES);

  const float invN = 1.0f / (float)N_NODES;
  const float invG = 1.0f / (float)N_GRAPHS;

  // ---- 5 GIN layers: agg(inline prev BN) -> MFMA GEMM(+stats into arena) ----
  for (int layer = 0; layer < 5; layer++) {
    const ushort* Wl = Wt + (size_t)layer * 128 * 128;
    const float* bl  = (layer == 0) ? b1 : bg + (size_t)(layer - 1) * 128;
    // prev layer's gamma/beta (for the inline normalize in agg of layer>=1)
    const float* pg  = (layer == 1) ? g1g : gg + (size_t)(layer - 2) * 128;
    const float* pb  = (layer == 1) ? g1b : gb + (size_t)(layer - 2) * 128;
    float* st = lsum + (size_t)layer * 256;

    if (layer == 0)
      k_agg_f<false><<<(N_NODES + 3) / 4, 256, 0, stream>>>(hb, row_ptr, csr,
                                                            nullptr, nullptr, nullptr, nullptr,
                                                            invN, Mb, N_NODES);
    else
      k_agg_f<true><<<(N_NODES + 3) / 4, 256, 0, stream>>>(yb, row_ptr, csr,
                                                           lsum + (size_t)(layer - 1) * 256,
                                                           lsum + (size_t)(layer - 1) * 256 + 128,
                                                           pg, pb, invN, Mb, N_NODES);
    k_gemm_mfma<<<(N_NODES + 127) / 128, 256, 0, stream>>>((const ushort*)Mb, Wl, bl, 2.0f,
                                                           (ushort*)yb, N_NODES,
                                                           st, st + 128);
  }

  // ---- readout (inline layer-5 BN+ReLU) ----
  k_readout<<<(N_NODES + 63) / 64, 64, 0, stream>>>(yb, gid,
                                                    lsum + 4 * 256, lsum + 4 * 256 + 128,
                                                    gg + 3 * 128, gb + 3 * 128, invN,
                                                    xg, N_NODES);

  // ---- fc1 (128 -> 512): fp32 A, fused stats ----
  k_head_mfma<0, 0><<<dim3(4, 16), 256, 0, stream>>>(xg, N_GRAPHS, 128, fc1Wt, fc1b, 0, 512,
                                                     nullptr, nullptr, y1b, 512, fsum1, fsq1);
  k_bnparams<<<1, 512, 0, stream>>>(fsum1, fsq1, bn1g, bn1b, Ac, Bc, 512, invG);

  // ---- lin (512 -> 256): bf16 A + inline bn1/relu, fused stats ----
  k_head_mfma<1, 0><<<dim3(2, 16), 256, 0, stream>>>(y1b, N_GRAPHS, 512, linWt, linb, 0, 256,
                                                     Ac, Bc, y2b, 256, lsum2, lsq2);
  k_bnparams<<<1, 256, 0, stream>>>(lsum2, lsq2, lbng, lbnb, Ac, Bc, 256, invG);

  // ---- fc2 (256 -> 204): bf16 A + inline lbn/relu, sigmoid, write out ----
  k_head_mfma<1, 1><<<dim3(2, 16), 256, 0, stream>>>(y2b, N_GRAPHS, 256, fc2Wt, fc2b, 204, NCLS,
                                                     Ac, Bc, out, NCLS, nullptr, nullptr);
}